// Round 3
// baseline (96.905 us; speedup 1.0000x reference)
//
#include <hip/hip_runtime.h>

// Problem constants (B=2, H=8, L=1024, D=64)
#define N_HEADS 16          // B*H
#define L_SEQ   1024
#define D_HEAD  64
#define D2      128         // 2*D (sin/cos concat)
#define T_CHUNK 64
#define N_CHUNK (L_SEQ / T_CHUNK)   // 16
#define KV_ELEMS (D2 * D_HEAD)      // 8192

// Padded LDS row: insert a 4-float gap every 32 columns so the 16 g-groups
// (2x float4 reads at 8-col offsets) spread across banks (2-way max = free).
#define ROWP 140
#define PARTP 132

__device__ __forceinline__ int pad_col(int d2) { return d2 + 4 * (d2 >> 5); }

#define SINCOS_SCALE 1.53398078788564122971e-3f   // (pi/2)/1024

// All-VALU (DPP) lane reductions; LDS pipe stays free for ds_read_b128.
// 0xB1 = quad_perm(1,0,3,2) = lane^1 ; 0x4E = quad_perm(2,3,0,1) = lane^2 ;
// 0x141 = row_half_mirror (acts as ^4 once quads are uniform) ;
// 0x140 = row_mirror (acts as ^8 once 8-groups are uniform).
__device__ __forceinline__ float red4_dpp(float x) {
    x += __int_as_float(__builtin_amdgcn_mov_dpp(__float_as_int(x), 0xB1, 0xF, 0xF, true));
    x += __int_as_float(__builtin_amdgcn_mov_dpp(__float_as_int(x), 0x4E, 0xF, 0xF, true));
    return x;
}
__device__ __forceinline__ float red16_dpp(float x) {
    x = red4_dpp(x);
    x += __int_as_float(__builtin_amdgcn_mov_dpp(__float_as_int(x), 0x141, 0xF, 0xF, true));
    x += __int_as_float(__builtin_amdgcn_mov_dpp(__float_as_int(x), 0x140, 0xF, 0xF, true));
    return x;
}

// ---------------------------------------------------------------------------
// K1: per-(chunk, head) local sums. 256 threads; thread owns 8 d2-cols
// (g = tid&15) x 4 m-cols (mq = tid>>4) -> 32 FMA per 12 LDS floats read.
// ---------------------------------------------------------------------------
__global__ __launch_bounds__(256, 1) void k1_chunk_sums(
    const float* __restrict__ k, const float* __restrict__ v,
    float* __restrict__ sumkv, float* __restrict__ sumk)
{
    __shared__ __attribute__((aligned(16))) float k_s[T_CHUNK][ROWP];
    __shared__ __attribute__((aligned(16))) float v_s[T_CHUNK][D_HEAD];
    __shared__ float s_tab[T_CHUNK], c_tab[T_CHUNK];
    __shared__ float halfsum[2][D2];

    const int c = blockIdx.x, n = blockIdx.y;
    const int tid = threadIdx.x;
    const int base = (n * L_SEQ + c * T_CHUNK) * D_HEAD;

    if (tid < T_CHUNK) {
        float th = SINCOS_SCALE * (float)(c * T_CHUNK + tid + 1);
        s_tab[tid] = __sinf(th);
        c_tab[tid] = __cosf(th);
    }
    __syncthreads();

    const float4* k4g = (const float4*)(k + base);
    const float4* v4g = (const float4*)(v + base);
#pragma unroll
    for (int j = 0; j < 4; ++j) {
        int i4 = j * 256 + tid;            // 0..1023
        int l = i4 >> 4, d = (i4 & 15) << 2;
        float4 kk = k4g[i4], vv = v4g[i4];
        kk.x = fmaxf(kk.x, 0.f); kk.y = fmaxf(kk.y, 0.f);
        kk.z = fmaxf(kk.z, 0.f); kk.w = fmaxf(kk.w, 0.f);
        vv.x = fmaxf(vv.x, 0.f); vv.y = fmaxf(vv.y, 0.f);
        vv.z = fmaxf(vv.z, 0.f); vv.w = fmaxf(vv.w, 0.f);
        float s = s_tab[l], cs = c_tab[l];
        *(float4*)&k_s[l][pad_col(d)]      = make_float4(kk.x*s,  kk.y*s,  kk.z*s,  kk.w*s);
        *(float4*)&k_s[l][pad_col(d + 64)] = make_float4(kk.x*cs, kk.y*cs, kk.z*cs, kk.w*cs);
        *(float4*)&v_s[l][d] = vv;
    }
    __syncthreads();

    // Column sums of k_ -> sumk (2-way parallel over l-halves).
    {
        int col = tid & 127, half = tid >> 7;
        int pc = pad_col(col);
        float s = 0.f;
#pragma unroll
        for (int i = 0; i < 32; ++i) s += k_s[half * 32 + i][pc];
        halfsum[half][col] = s;
    }
    __syncthreads();
    if (tid < D2) sumk[(n * N_CHUNK + c) * D2 + tid] = halfsum[0][tid] + halfsum[1][tid];

    const int g = tid & 15, mb = (tid >> 4) << 2;
    const int gbase = pad_col(8 * g);

    float st[8][4];
#pragma unroll
    for (int i = 0; i < 8; ++i)
#pragma unroll
        for (int j = 0; j < 4; ++j) st[i][j] = 0.f;

    for (int l = 0; l < T_CHUNK; ++l) {
        float4 vv = *(const float4*)&v_s[l][mb];
        const float4* kf4 = (const float4*)&k_s[l][gbase];
        float4 ka = kf4[0], kb = kf4[1];
        float kf[8] = {ka.x, ka.y, ka.z, ka.w, kb.x, kb.y, kb.z, kb.w};
#pragma unroll
        for (int i = 0; i < 8; ++i) {
            st[i][0] = fmaf(kf[i], vv.x, st[i][0]);
            st[i][1] = fmaf(kf[i], vv.y, st[i][1]);
            st[i][2] = fmaf(kf[i], vv.z, st[i][2]);
            st[i][3] = fmaf(kf[i], vv.w, st[i][3]);
        }
    }

    // Coalesced float4 stores, thread-interleaved flat layout (K3 mirrors it).
    float4* dst = (float4*)(sumkv + (size_t)(n * N_CHUNK + c) * KV_ELEMS);
#pragma unroll
    for (int i = 0; i < 8; ++i)
        dst[i * 256 + tid] = make_float4(st[i][0], st[i][1], st[i][2], st[i][3]);
}

// ---------------------------------------------------------------------------
// K2: exclusive prefix over 16 chunks, 1 elem/thread, fully unrolled
// 16-deep load pipeline (data-independent addresses -> MLP).
// ---------------------------------------------------------------------------
__global__ __launch_bounds__(256) void k2_prefix(
    float* __restrict__ sumkv, float* __restrict__ sumk)
{
    const int x = blockIdx.x, n = blockIdx.y;
    const int tid = threadIdx.x;

    if (x < 32) {
        float* base = sumkv + (size_t)n * N_CHUNK * KV_ELEMS + x * 256 + tid;
        float t[N_CHUNK];
#pragma unroll
        for (int c = 0; c < N_CHUNK; ++c) t[c] = base[c * KV_ELEMS];
        float r = 0.f;
#pragma unroll
        for (int c = 0; c < N_CHUNK; ++c) { base[c * KV_ELEMS] = r; r += t[c]; }
    } else if (tid < D2) {
        float* bk = sumk + n * N_CHUNK * D2 + tid;
        float t[N_CHUNK];
#pragma unroll
        for (int c = 0; c < N_CHUNK; ++c) t[c] = bk[c * D2];
        float r = 0.f;
#pragma unroll
        for (int c = 0; c < N_CHUNK; ++c) { bk[c * D2] = r; r += t[c]; }
    }
}

// ---------------------------------------------------------------------------
// K3: outputs. 256 threads, (8 d2-cols x 4 m-cols)/thread, DPP red16,
// denominator precomputed once per block; part_s overlaid with out_s.
// ---------------------------------------------------------------------------
__global__ __launch_bounds__(256, 1) void k3_output(
    const float* __restrict__ q, const float* __restrict__ k,
    const float* __restrict__ v, const float* __restrict__ sumkv,
    const float* __restrict__ sumk, float* __restrict__ out)
{
    __shared__ __attribute__((aligned(16))) float k_s[T_CHUNK][ROWP];
    __shared__ __attribute__((aligned(16))) float q_s[T_CHUNK][ROWP];
    __shared__ __attribute__((aligned(16))) float v_s[T_CHUNK][D_HEAD];
    __shared__ __attribute__((aligned(16))) float pool[T_CHUNK * PARTP]; // part_s / out_s
    __shared__ float rden_s[T_CHUNK];
    __shared__ float s_tab[T_CHUNK], c_tab[T_CHUNK];
    __shared__ float halfsum[2][D2];

    float (*part_s)[PARTP]  = (float(*)[PARTP])pool;
    float (*out_s)[D_HEAD]  = (float(*)[D_HEAD])pool;

    const int c = blockIdx.x, n = blockIdx.y;
    const int tid = threadIdx.x;
    const int base = (n * L_SEQ + c * T_CHUNK) * D_HEAD;

    if (tid < T_CHUNK) {
        float th = SINCOS_SCALE * (float)(c * T_CHUNK + tid + 1);
        s_tab[tid] = __sinf(th);
        c_tab[tid] = __cosf(th);
    }
    __syncthreads();

    const float4* q4g = (const float4*)(q + base);
    const float4* k4g = (const float4*)(k + base);
    const float4* v4g = (const float4*)(v + base);
#pragma unroll
    for (int j = 0; j < 4; ++j) {
        int i4 = j * 256 + tid;
        int l = i4 >> 4, d = (i4 & 15) << 2;
        float4 kk = k4g[i4], qq = q4g[i4], vv = v4g[i4];
        kk.x = fmaxf(kk.x, 0.f); kk.y = fmaxf(kk.y, 0.f);
        kk.z = fmaxf(kk.z, 0.f); kk.w = fmaxf(kk.w, 0.f);
        qq.x = fmaxf(qq.x, 0.f); qq.y = fmaxf(qq.y, 0.f);
        qq.z = fmaxf(qq.z, 0.f); qq.w = fmaxf(qq.w, 0.f);
        vv.x = fmaxf(vv.x, 0.f); vv.y = fmaxf(vv.y, 0.f);
        vv.z = fmaxf(vv.z, 0.f); vv.w = fmaxf(vv.w, 0.f);
        float s = s_tab[l], cs = c_tab[l];
        *(float4*)&k_s[l][pad_col(d)]      = make_float4(kk.x*s,  kk.y*s,  kk.z*s,  kk.w*s);
        *(float4*)&k_s[l][pad_col(d + 64)] = make_float4(kk.x*cs, kk.y*cs, kk.z*cs, kk.w*cs);
        *(float4*)&q_s[l][pad_col(d)]      = make_float4(qq.x*s,  qq.y*s,  qq.z*s,  qq.w*s);
        *(float4*)&q_s[l][pad_col(d + 64)] = make_float4(qq.x*cs, qq.y*cs, qq.z*cs, qq.w*cs);
        *(float4*)&v_s[l][d] = vv;
    }

    // Prefix state loads issued here: overlap the LDS phases below.
    const float4* pkv = (const float4*)(sumkv + (size_t)(n * N_CHUNK + c) * KV_ELEMS);
    float st[8][4];
#pragma unroll
    for (int i = 0; i < 8; ++i) {
        float4 p = pkv[i * 256 + tid];
        st[i][0] = p.x; st[i][1] = p.y; st[i][2] = p.z; st[i][3] = p.w;
    }
    float kc_g = sumk[(n * N_CHUNK + c) * D2 + (tid & 127)];

    __syncthreads();

    // Denominator pass A: per-half column sums of k_ (carry for half 1).
    {
        int col = tid & 127, half = tid >> 7;
        int pc = pad_col(col);
        float s = 0.f;
#pragma unroll
        for (int i = 0; i < 32; ++i) s += k_s[half * 32 + i][pc];
        halfsum[half][col] = s;
    }
    __syncthreads();

    // Pass B: running column cumsum * q -> part_s (both halves in parallel).
    {
        int col = tid & 127, half = tid >> 7;
        int pc = pad_col(col);
        float kc = kc_g + (half ? halfsum[0][col] : 0.f);
#pragma unroll
        for (int i = 0; i < 32; ++i) {
            int l = half * 32 + i;
            kc += k_s[l][pc];
            part_s[l][col] = q_s[l][pc] * kc;
        }
    }
    __syncthreads();

    // Row-reduce part_s -> 1/den. 4 lanes per row, DPP quad reduce.
    {
        int l = tid >> 2, j = tid & 3;
        const float4* p4 = (const float4*)&part_s[l][j * 32];
        float sum = 0.f;
#pragma unroll
        for (int t = 0; t < 8; ++t) {
            float4 x = p4[t];
            sum += (x.x + x.y) + (x.z + x.w);
        }
        sum = red4_dpp(sum);
        if (j == 0) rden_s[l] = 1.f / fmaxf(sum, 1e-6f);
    }
    __syncthreads();   // part_s dead; pool becomes out_s

    const int g = tid & 15, mb = (tid >> 4) << 2;
    const int gbase = pad_col(8 * g);

    for (int l = 0; l < T_CHUNK; ++l) {
        float4 vv = *(const float4*)&v_s[l][mb];
        const float4* kf4 = (const float4*)&k_s[l][gbase];
        const float4* qf4 = (const float4*)&q_s[l][gbase];
        float4 ka = kf4[0], kb = kf4[1];
        float4 qa = qf4[0], qb = qf4[1];
        float kf[8] = {ka.x, ka.y, ka.z, ka.w, kb.x, kb.y, kb.z, kb.w};
        float qf[8] = {qa.x, qa.y, qa.z, qa.w, qb.x, qb.y, qb.z, qb.w};
        float a0 = 0.f, a1 = 0.f, a2 = 0.f, a3 = 0.f;
#pragma unroll
        for (int i = 0; i < 8; ++i) {
            st[i][0] = fmaf(kf[i], vv.x, st[i][0]); a0 = fmaf(qf[i], st[i][0], a0);
            st[i][1] = fmaf(kf[i], vv.y, st[i][1]); a1 = fmaf(qf[i], st[i][1], a1);
            st[i][2] = fmaf(kf[i], vv.z, st[i][2]); a2 = fmaf(qf[i], st[i][2], a2);
            st[i][3] = fmaf(kf[i], vv.w, st[i][3]); a3 = fmaf(qf[i], st[i][3], a3);
        }
        a0 = red16_dpp(a0);
        a1 = red16_dpp(a1);
        a2 = red16_dpp(a2);
        a3 = red16_dpp(a3);
        if (g == 0) {
            float r = rden_s[l];
            *(float4*)&out_s[l][mb] = make_float4(a0 * r, a1 * r, a2 * r, a3 * r);
        }
    }
    __syncthreads();

    // Coalesced output store.
    {
        float4* o4 = (float4*)(out + base);
        const float4* s4o = (const float4*)&out_s[0][0];
#pragma unroll
        for (int j = 0; j < 4; ++j) o4[j * 256 + tid] = s4o[j * 256 + tid];
    }
}

// ---------------------------------------------------------------------------
extern "C" void kernel_launch(void* const* d_in, const int* in_sizes, int n_in,
                              void* d_out, int out_size, void* d_ws, size_t ws_size,
                              hipStream_t stream) {
    (void)in_sizes; (void)n_in; (void)out_size; (void)ws_size;
    const float* q = (const float*)d_in[0];
    const float* k = (const float*)d_in[1];
    const float* v = (const float*)d_in[2];
    float* out = (float*)d_out;

    float* sumkv = (float*)d_ws;                                   // [N][C][8192] flat
    float* sumk  = sumkv + (size_t)N_HEADS * N_CHUNK * KV_ELEMS;   // [N][C][128]

    dim3 grid(N_CHUNK, N_HEADS);
    k1_chunk_sums<<<grid, 256, 0, stream>>>(k, v, sumkv, sumk);
    dim3 grid2(33, N_HEADS);
    k2_prefix<<<grid2, 256, 0, stream>>>(sumkv, sumk);
    k3_output<<<grid, 256, 0, stream>>>(q, k, v, sumkv, sumk, out);
}

// Round 4
// 92.549 us; speedup vs baseline: 1.0471x; 1.0471x over previous
//
#include <hip/hip_runtime.h>

// Problem constants (B=2, H=8, L=1024, D=64)
#define N_HEADS 16          // B*H
#define L_SEQ   1024
#define D_HEAD  64
#define D2      128         // 2*D (sin/cos concat)
#define T_CHUNK 32
#define N_CHUNK (L_SEQ / T_CHUNK)   // 32
#define KV_ELEMS (D2 * D_HEAD)      // 8192

// Padded LDS row: insert a 4-float gap every 32 columns; the 16 g-groups'
// b128 reads then hit each bank at most 2-way (free, m136).
#define ROWP 140
#define PARTP 132

__device__ __forceinline__ int pad_col(int d2) { return d2 + 4 * (d2 >> 5); }

#define SINCOS_SCALE 1.53398078788564122971e-3f   // (pi/2)/1024

// All-VALU (DPP) lane reductions; LDS pipe stays free for ds_read_b128.
// 0xB1 = quad_perm lane^1 ; 0x4E = quad_perm lane^2 ;
// 0x141 = row_half_mirror (^4 once quads uniform) ;
// 0x140 = row_mirror (^8 once 8-groups uniform).
__device__ __forceinline__ float red8_dpp(float x) {
    x += __int_as_float(__builtin_amdgcn_mov_dpp(__float_as_int(x), 0xB1, 0xF, 0xF, true));
    x += __int_as_float(__builtin_amdgcn_mov_dpp(__float_as_int(x), 0x4E, 0xF, 0xF, true));
    x += __int_as_float(__builtin_amdgcn_mov_dpp(__float_as_int(x), 0x141, 0xF, 0xF, true));
    return x;
}
__device__ __forceinline__ float red16_dpp(float x) {
    x += __int_as_float(__builtin_amdgcn_mov_dpp(__float_as_int(x), 0xB1, 0xF, 0xF, true));
    x += __int_as_float(__builtin_amdgcn_mov_dpp(__float_as_int(x), 0x4E, 0xF, 0xF, true));
    x += __int_as_float(__builtin_amdgcn_mov_dpp(__float_as_int(x), 0x141, 0xF, 0xF, true));
    x += __int_as_float(__builtin_amdgcn_mov_dpp(__float_as_int(x), 0x140, 0xF, 0xF, true));
    return x;
}

// ---------------------------------------------------------------------------
// K1: per-(chunk, head) local sums. 256 threads; thread owns 8 d2-cols
// (g = tid&15) x 4 m-cols (mb) -> 32 FMA per 3 ds_read_b128.
// ---------------------------------------------------------------------------
__global__ __launch_bounds__(256, 2) void k1_chunk_sums(
    const float* __restrict__ k, const float* __restrict__ v,
    float* __restrict__ sumkv, float* __restrict__ sumk)
{
    __shared__ __attribute__((aligned(16))) float k_s[T_CHUNK][ROWP];
    __shared__ __attribute__((aligned(16))) float v_s[T_CHUNK][D_HEAD];
    __shared__ float s_tab[T_CHUNK], c_tab[T_CHUNK];

    const int c = blockIdx.x, n = blockIdx.y;
    const int tid = threadIdx.x;
    const int base = (n * L_SEQ + c * T_CHUNK) * D_HEAD;

    if (tid < T_CHUNK) {
        float th = SINCOS_SCALE * (float)(c * T_CHUNK + tid + 1);
        s_tab[tid] = __sinf(th);
        c_tab[tid] = __cosf(th);
    }
    __syncthreads();

    const float4* k4g = (const float4*)(k + base);
    const float4* v4g = (const float4*)(v + base);
#pragma unroll
    for (int j = 0; j < 2; ++j) {
        int i4 = j * 256 + tid;            // 0..511
        int l = i4 >> 4, d = (i4 & 15) << 2;
        float4 kk = k4g[i4], vv = v4g[i4];
        kk.x = fmaxf(kk.x, 0.f); kk.y = fmaxf(kk.y, 0.f);
        kk.z = fmaxf(kk.z, 0.f); kk.w = fmaxf(kk.w, 0.f);
        vv.x = fmaxf(vv.x, 0.f); vv.y = fmaxf(vv.y, 0.f);
        vv.z = fmaxf(vv.z, 0.f); vv.w = fmaxf(vv.w, 0.f);
        float s = s_tab[l], cs = c_tab[l];
        *(float4*)&k_s[l][pad_col(d)]      = make_float4(kk.x*s,  kk.y*s,  kk.z*s,  kk.w*s);
        *(float4*)&k_s[l][pad_col(d + 64)] = make_float4(kk.x*cs, kk.y*cs, kk.z*cs, kk.w*cs);
        *(float4*)&v_s[l][d] = vv;
    }
    __syncthreads();

    // Column sums of k_ -> sumk, computed once.
    if (tid < D2) {
        int pc = pad_col(tid);
        float ks = 0.f;
#pragma unroll
        for (int l = 0; l < T_CHUNK; ++l) ks += k_s[l][pc];
        sumk[(n * N_CHUNK + c) * D2 + tid] = ks;
    }

    const int g = tid & 15, mb = (tid >> 4) << 2;
    const int gbase = pad_col(8 * g);

    float st[8][4];
#pragma unroll
    for (int i = 0; i < 8; ++i)
#pragma unroll
        for (int j = 0; j < 4; ++j) st[i][j] = 0.f;

    for (int l = 0; l < T_CHUNK; ++l) {
        float4 vv = *(const float4*)&v_s[l][mb];
        const float4* kf4 = (const float4*)&k_s[l][gbase];
        float4 ka = kf4[0], kb = kf4[1];
        float kf[8] = {ka.x, ka.y, ka.z, ka.w, kb.x, kb.y, kb.z, kb.w};
#pragma unroll
        for (int i = 0; i < 8; ++i) {
            st[i][0] = fmaf(kf[i], vv.x, st[i][0]);
            st[i][1] = fmaf(kf[i], vv.y, st[i][1]);
            st[i][2] = fmaf(kf[i], vv.z, st[i][2]);
            st[i][3] = fmaf(kf[i], vv.w, st[i][3]);
        }
    }

    // Coalesced float4 stores, thread-interleaved flat layout (K3 mirrors it).
    float4* dst = (float4*)(sumkv + (size_t)(n * N_CHUNK + c) * KV_ELEMS);
#pragma unroll
    for (int i = 0; i < 8; ++i)
        dst[i * 256 + tid] = make_float4(st[i][0], st[i][1], st[i][2], st[i][3]);
}

// ---------------------------------------------------------------------------
// K2: exclusive prefix over chunks, 1 elem/thread, fully unrolled 32-deep
// load pipeline (data-independent addresses -> memory-level parallelism).
// ---------------------------------------------------------------------------
__global__ __launch_bounds__(256) void k2_prefix(
    float* __restrict__ sumkv, float* __restrict__ sumk)
{
    const int x = blockIdx.x, n = blockIdx.y;
    const int tid = threadIdx.x;

    if (x < 32) {
        float* base = sumkv + (size_t)n * N_CHUNK * KV_ELEMS + x * 256 + tid;
        float t[N_CHUNK];
#pragma unroll
        for (int c = 0; c < N_CHUNK; ++c) t[c] = base[c * KV_ELEMS];
        float r = 0.f;
#pragma unroll
        for (int c = 0; c < N_CHUNK; ++c) { base[c * KV_ELEMS] = r; r += t[c]; }
    } else if (tid < D2) {
        float* bk = sumk + n * N_CHUNK * D2 + tid;
        float t[N_CHUNK];
#pragma unroll
        for (int c = 0; c < N_CHUNK; ++c) t[c] = bk[c * D2];
        float r = 0.f;
#pragma unroll
        for (int c = 0; c < N_CHUNK; ++c) { bk[c * D2] = r; r += t[c]; }
    }
}

// ---------------------------------------------------------------------------
// K3: outputs. 256 threads, (8 d2-cols x 4 m-cols)/thread, DPP red16,
// denominator precomputed once per block; part_s overlaid with out_s.
// ---------------------------------------------------------------------------
__global__ __launch_bounds__(256, 2) void k3_output(
    const float* __restrict__ q, const float* __restrict__ k,
    const float* __restrict__ v, const float* __restrict__ sumkv,
    const float* __restrict__ sumk, float* __restrict__ out)
{
    __shared__ __attribute__((aligned(16))) float k_s[T_CHUNK][ROWP];
    __shared__ __attribute__((aligned(16))) float q_s[T_CHUNK][ROWP];
    __shared__ __attribute__((aligned(16))) float v_s[T_CHUNK][D_HEAD];
    __shared__ __attribute__((aligned(16))) float pool[T_CHUNK * PARTP]; // part_s / out_s
    __shared__ float rden_s[T_CHUNK];
    __shared__ float s_tab[T_CHUNK], c_tab[T_CHUNK];

    float (*part_s)[PARTP] = (float(*)[PARTP])pool;
    float (*out_s)[D_HEAD] = (float(*)[D_HEAD])pool;

    const int c = blockIdx.x, n = blockIdx.y;
    const int tid = threadIdx.x;
    const int base = (n * L_SEQ + c * T_CHUNK) * D_HEAD;

    if (tid < T_CHUNK) {
        float th = SINCOS_SCALE * (float)(c * T_CHUNK + tid + 1);
        s_tab[tid] = __sinf(th);
        c_tab[tid] = __cosf(th);
    }
    __syncthreads();

    const float4* q4g = (const float4*)(q + base);
    const float4* k4g = (const float4*)(k + base);
    const float4* v4g = (const float4*)(v + base);
#pragma unroll
    for (int j = 0; j < 2; ++j) {
        int i4 = j * 256 + tid;
        int l = i4 >> 4, d = (i4 & 15) << 2;
        float4 kk = k4g[i4], qq = q4g[i4], vv = v4g[i4];
        kk.x = fmaxf(kk.x, 0.f); kk.y = fmaxf(kk.y, 0.f);
        kk.z = fmaxf(kk.z, 0.f); kk.w = fmaxf(kk.w, 0.f);
        qq.x = fmaxf(qq.x, 0.f); qq.y = fmaxf(qq.y, 0.f);
        qq.z = fmaxf(qq.z, 0.f); qq.w = fmaxf(qq.w, 0.f);
        vv.x = fmaxf(vv.x, 0.f); vv.y = fmaxf(vv.y, 0.f);
        vv.z = fmaxf(vv.z, 0.f); vv.w = fmaxf(vv.w, 0.f);
        float s = s_tab[l], cs = c_tab[l];
        *(float4*)&k_s[l][pad_col(d)]      = make_float4(kk.x*s,  kk.y*s,  kk.z*s,  kk.w*s);
        *(float4*)&k_s[l][pad_col(d + 64)] = make_float4(kk.x*cs, kk.y*cs, kk.z*cs, kk.w*cs);
        *(float4*)&q_s[l][pad_col(d)]      = make_float4(qq.x*s,  qq.y*s,  qq.z*s,  qq.w*s);
        *(float4*)&q_s[l][pad_col(d + 64)] = make_float4(qq.x*cs, qq.y*cs, qq.z*cs, qq.w*cs);
        *(float4*)&v_s[l][d] = vv;
    }

    // Prefix state loads issued before the barrier (latency overlap).
    const float4* pkv = (const float4*)(sumkv + (size_t)(n * N_CHUNK + c) * KV_ELEMS);
    float st[8][4];
#pragma unroll
    for (int i = 0; i < 8; ++i) {
        float4 p = pkv[i * 256 + tid];
        st[i][0] = p.x; st[i][1] = p.y; st[i][2] = p.z; st[i][3] = p.w;
    }
    float kc = 0.f;
    if (tid < D2) kc = sumk[(n * N_CHUNK + c) * D2 + tid];

    __syncthreads();

    // Denominator: per-column running k-cumsum * q, once per block.
    if (tid < D2) {
        int pc = pad_col(tid);
#pragma unroll
        for (int l = 0; l < T_CHUNK; ++l) {
            kc += k_s[l][pc];
            part_s[l][tid] = q_s[l][pc] * kc;
        }
    }
    __syncthreads();

    {
        int l = tid >> 3, j = tid & 7;
        const float4* p4 = (const float4*)&part_s[l][j * 16];
        float4 aa = p4[0], bb = p4[1], cc = p4[2], dd = p4[3];
        float sum = ((aa.x + aa.y) + (aa.z + aa.w)) + ((bb.x + bb.y) + (bb.z + bb.w))
                  + ((cc.x + cc.y) + (cc.z + cc.w)) + ((dd.x + dd.y) + (dd.z + dd.w));
        sum = red8_dpp(sum);
        if (j == 0) rden_s[l] = 1.f / fmaxf(sum, 1e-6f);
    }
    __syncthreads();   // part_s dead; pool becomes out_s

    const int g = tid & 15, mb = (tid >> 4) << 2;
    const int gbase = pad_col(8 * g);

    for (int l = 0; l < T_CHUNK; ++l) {
        float4 vv = *(const float4*)&v_s[l][mb];
        const float4* kf4 = (const float4*)&k_s[l][gbase];
        const float4* qf4 = (const float4*)&q_s[l][gbase];
        float4 ka = kf4[0], kb = kf4[1];
        float4 qa = qf4[0], qb = qf4[1];
        float kf[8] = {ka.x, ka.y, ka.z, ka.w, kb.x, kb.y, kb.z, kb.w};
        float qf[8] = {qa.x, qa.y, qa.z, qa.w, qb.x, qb.y, qb.z, qb.w};
        float a0 = 0.f, a1 = 0.f, a2 = 0.f, a3 = 0.f;
#pragma unroll
        for (int i = 0; i < 8; ++i) {
            st[i][0] = fmaf(kf[i], vv.x, st[i][0]); a0 = fmaf(qf[i], st[i][0], a0);
            st[i][1] = fmaf(kf[i], vv.y, st[i][1]); a1 = fmaf(qf[i], st[i][1], a1);
            st[i][2] = fmaf(kf[i], vv.z, st[i][2]); a2 = fmaf(qf[i], st[i][2], a2);
            st[i][3] = fmaf(kf[i], vv.w, st[i][3]); a3 = fmaf(qf[i], st[i][3], a3);
        }
        a0 = red16_dpp(a0);
        a1 = red16_dpp(a1);
        a2 = red16_dpp(a2);
        a3 = red16_dpp(a3);
        if (g == 0) {
            float r = rden_s[l];
            *(float4*)&out_s[l][mb] = make_float4(a0 * r, a1 * r, a2 * r, a3 * r);
        }
    }
    __syncthreads();

    // Coalesced output store.
    {
        float4* o4 = (float4*)(out + base);
        const float4* s4o = (const float4*)&out_s[0][0];
        o4[tid] = s4o[tid];
        o4[256 + tid] = s4o[256 + tid];
    }
}

// ---------------------------------------------------------------------------
extern "C" void kernel_launch(void* const* d_in, const int* in_sizes, int n_in,
                              void* d_out, int out_size, void* d_ws, size_t ws_size,
                              hipStream_t stream) {
    (void)in_sizes; (void)n_in; (void)out_size; (void)ws_size;
    const float* q = (const float*)d_in[0];
    const float* k = (const float*)d_in[1];
    const float* v = (const float*)d_in[2];
    float* out = (float*)d_out;

    float* sumkv = (float*)d_ws;                                   // [N][C][8192] flat
    float* sumk  = sumkv + (size_t)N_HEADS * N_CHUNK * KV_ELEMS;   // [N][C][128]

    dim3 grid(N_CHUNK, N_HEADS);
    k1_chunk_sums<<<grid, 256, 0, stream>>>(k, v, sumkv, sumk);
    dim3 grid2(33, N_HEADS);
    k2_prefix<<<grid2, 256, 0, stream>>>(sumkv, sumk);
    k3_output<<<grid, 256, 0, stream>>>(q, k, v, sumkv, sumk, out);
}